// Round 3
// baseline (187.126 us; speedup 1.0000x reference)
//
#include <hip/hip_runtime.h>

#define B_  8
#define QL_ 128
#define ML_ 1024
#define KS_ 512
#define H_  256

// ws layout (floats):
//   Eq = exp2(2log2e * qproj): [B][QL][H]  @ 0        (262144 floats)
//   Ek = exp2(2log2e * kproj): [B][ML][H]  @ 262144   (2097152 floats)
//   mask canonical uint8 [B*ML]            @ 2359296  (8192 bytes = 2048 floats)
//   Whi bf16 [512][512]                    @ 2361344  (131072 floats)
//   Wlo bf16 [512][512]                    @ 2492416  (131072 floats)
#define QP_OFF 0
#define KP_OFF 262144
#define MASK_OFF 2359296
#define WH_OFF 2361344
#define WL_OFF 2492416

typedef __attribute__((ext_vector_type(8))) short bfrag;   // 8 bf16 (4 VGPR)
typedef __attribute__((ext_vector_type(4))) float f4acc;   // MFMA acc

// fp32 -> (hi,lo) bf16 split. hi = truncation (residual <= 2^-8|x|, captured
// exactly by fp32 subtract); lo = RNE of residual (final err <= 2^-17|x|).
// Dropped lo*lo cross term <= 2^-16 rel. Same math as R2 (bit-identical).
__device__ __forceinline__ void split1(float v, unsigned& h, unsigned& lo) {
    unsigned u  = __float_as_uint(v);
    unsigned hb = u & 0xFFFF0000u;
    float    lf = v - __uint_as_float(hb);           // exact
    unsigned ul = __float_as_uint(lf);
    unsigned lr = ul + 0x7FFFu + ((ul >> 16) & 1u);  // RNE
    h  = u >> 16;
    lo = lr >> 16;
}

__device__ __forceinline__ void split4(const float4& a, unsigned& h01, unsigned& h23,
                                       unsigned& l01, unsigned& l23) {
    unsigned h[4], l[4];
    split1(a.x, h[0], l[0]); split1(a.y, h[1], l[1]);
    split1(a.z, h[2], l[2]); split1(a.w, h[3], l[3]);
    h01 = h[0] | (h[1] << 16); h23 = h[2] | (h[3] << 16);
    l01 = l[0] | (l[1] << 16); l23 = l[2] | (l[3] << 16);
}

// ---------------------------------------------------------------------------
// Prep kernel: one-time W split (W re-split per-block was 144x redundant VALU
// in R2) + mask canonicalizer. Grid 65 x 256.
//   bid 0..31 : Wq (256x512) -> Whi/Wlo rows 0..255
//   bid 32..63: Wk (256x512) -> Whi/Wlo rows 256..511
//   bid 64    : mask canonicalizer
// Each thread: 16 contiguous elements (4 float4 loads -> 2+2 uint4 stores).
// ---------------------------------------------------------------------------
__global__ __launch_bounds__(256) void prep_kernel(
    const float* __restrict__ Wq, const float* __restrict__ Wk,
    unsigned short* __restrict__ Whi, unsigned short* __restrict__ Wlo,
    const unsigned char* __restrict__ mraw, unsigned char* __restrict__ mout) {
    const int bid = blockIdx.x;
    const int t = threadIdx.x;

    if (bid == 64) {   // ---- mask canonicalizer ----
        __shared__ int s_not01, s_not0f;
        const unsigned int* w = (const unsigned int*)mraw;
        if (t == 0) { s_not01 = 0; s_not0f = 0; }
        __syncthreads();
        int not01 = 0, not0f = 0;
        for (int i = t; i < 2048; i += 256) {
            unsigned int v = w[i];
            if (v != 0u && v != 1u) not01 = 1;
            if (v != 0u && v != 0x3F800000u) not0f = 1;
        }
        if (not01) atomicOr(&s_not01, 1);
        if (not0f) atomicOr(&s_not0f, 1);
        __syncthreads();
        int wordTyped = (!s_not01) || (!s_not0f);
        for (int i = t; i < B_ * ML_; i += 256) {
            unsigned char mv;
            if (wordTyped) mv = (w[i] != 0u) ? 1 : 0;
            else           mv = mraw[i] ? 1 : 0;
            mout[i] = mv;
        }
        return;
    }

    const float* src = (bid < 32) ? Wq : Wk;
    const int lb = bid & 31;
    const size_t loff = (size_t)lb * 4096 + (size_t)t * 16;       // element idx in matrix
    const size_t doff = ((bid < 32) ? 0 : 131072) + loff;          // element idx in planes

    unsigned hw[8], lw[8];
#pragma unroll
    for (int i = 0; i < 4; ++i) {
        float4 v = *(const float4*)(src + loff + i * 4);
        split4(v, hw[i * 2], hw[i * 2 + 1], lw[i * 2], lw[i * 2 + 1]);
    }
    *(uint4*)(Whi + doff)     = make_uint4(hw[0], hw[1], hw[2], hw[3]);
    *(uint4*)(Whi + doff + 8) = make_uint4(hw[4], hw[5], hw[6], hw[7]);
    *(uint4*)(Wlo + doff)     = make_uint4(lw[0], lw[1], lw[2], lw[3]);
    *(uint4*)(Wlo + doff + 8) = make_uint4(lw[4], lw[5], lw[6], lw[7]);
}

// ---------------------------------------------------------------------------
// Projection via bf16x3-split MFMA.
// R2 failed schedule: 145 blocks x 1 wave/SIMD, inline split of BOTH operands
// (~600 VALU : 48 MFMA per chunk, no co-issue partner) -> ~42 us. Fix:
//  * B operand pre-split (prep_kernel) -> pure 16B L2 loads, zero VALU.
//  * A split ONCE per block into LDS (1 thread : 1 float4 per chunk),
//    read back as swizzled ds_read_b128 (2-way max = free).
//  * Grid 576 blocks (32m x 128n; wave = 32m x 32n; acc = 16 VGPR)
//    -> 2.25 waves/SIMD: VALU/MFMA/VMEM co-schedule across waves.
// Ping-pong LDS, 2 barriers/chunk, A and B register-prefetched 1 chunk ahead.
// Same split math + same MFMA accumulation order as R2 -> bit-identical out.
// frag layout (m89-family): A lane l -> row l&15, k=8*(l>>4)+j; C/D col=l&15,
// row=(l>>4)*4+reg.
// ---------------------------------------------------------------------------
__global__ __launch_bounds__(256) void proj_kernel(
    const float* __restrict__ query, const float* __restrict__ memory,
    const unsigned short* __restrict__ Whi, const unsigned short* __restrict__ Wlo,
    const float* __restrict__ bq, const float* __restrict__ bk,
    float* __restrict__ Eq, float* __restrict__ Ek) {
    const int bid = blockIdx.x;
    const int t = threadIdx.x;
    const int nb = bid & 1;          // n half: cols [nb*128, nb*128+128)
    const int mb = bid >> 1;         // m tile of 32 rows (0..287)

    const float *X, *bias; float* out; int row0, wbase0;
    if (mb < 32) { X = query;  bias = bq; out = Eq; row0 = mb * 32;        wbase0 = 0; }
    else         { X = memory; bias = bk; out = Ek; row0 = (mb - 32) * 32; wbase0 = 256; }

    const int w  = t >> 6;    // wave id -> n sub-block of 32
    const int l  = t & 63;
    const int lr = l & 15;    // frag row/col within 16-tile
    const int lk = l >> 4;    // k-group (8 els) within 32-chunk

    // ---- A staging map: thread t loads X[row0 + (t>>3)][c*32 + (t&7)*4 ..+3]
    const int arow = t >> 3;          // 0..31
    const int acol = (t & 7) << 2;    // 0,4,..,28
    const float* Xp = X + (size_t)(row0 + arow) * 512 + acol;
    // LDS: [buf][row][16 u32-words = 32 bf16]; group (4 words/16B) swizzled by
    // g ^= (row>>1)&3  -> read pattern is 2-way max (free per m136).
    __shared__ unsigned int AH[2][32][16];
    __shared__ unsigned int AL[2][32][16];
    const int wg  = ((t & 7) >> 1) ^ ((arow >> 1) & 3);  // swizzled write group
    const int wwo = ((t & 7) & 1) << 1;                  // word pair within group

    // ---- B pointers (L2-resident pre-split planes)
    const int wrow0 = wbase0 + nb * 128 + w * 32;
    const unsigned short* bhP0 = Whi + (size_t)(wrow0 + 0 * 16 + lr) * 512 + lk * 8;
    const unsigned short* bhP1 = Whi + (size_t)(wrow0 + 1 * 16 + lr) * 512 + lk * 8;
    const unsigned short* blP0 = Wlo + (size_t)(wrow0 + 0 * 16 + lr) * 512 + lk * 8;
    const unsigned short* blP1 = Wlo + (size_t)(wrow0 + 1 * 16 + lr) * 512 + lk * 8;

    f4acc acc[2][2];
#pragma unroll
    for (int mi = 0; mi < 2; ++mi)
#pragma unroll
        for (int ni = 0; ni < 2; ++ni)
            acc[mi][ni] = (f4acc){0.f, 0.f, 0.f, 0.f};

#define WRA(P, XA) do {                                               \
    unsigned h01, h23, l01, l23;                                      \
    split4(XA, h01, h23, l01, l23);                                   \
    unsigned int* dh = &AH[P][arow][wg * 4 + wwo];                    \
    unsigned int* dl = &AL[P][arow][wg * 4 + wwo];                    \
    dh[0] = h01; dh[1] = h23; dl[0] = l01; dl[1] = l23; } while (0)

#define LDB(BH0, BH1, BL0, BL1, c) do {                               \
    BH0 = *(const uint4*)(bhP0 + (size_t)(c) * 32);                   \
    BH1 = *(const uint4*)(bhP1 + (size_t)(c) * 32);                   \
    BL0 = *(const uint4*)(blP0 + (size_t)(c) * 32);                   \
    BL1 = *(const uint4*)(blP1 + (size_t)(c) * 32); } while (0)

#define COMP(P, BH0, BH1, BL0, BL1) do {                              \
    bfrag ah[2], al[2];                                               \
    _Pragma("unroll")                                                 \
    for (int mi = 0; mi < 2; ++mi) {                                  \
        int ra = mi * 16 + lr;                                        \
        int g4 = (lk ^ ((ra >> 1) & 3)) * 4;                          \
        ah[mi] = *(const bfrag*)&AH[P][ra][g4];                       \
        al[mi] = *(const bfrag*)&AL[P][ra][g4];                       \
    }                                                                 \
    bfrag bh[2], bl[2];                                               \
    bh[0] = __builtin_bit_cast(bfrag, BH0);                           \
    bh[1] = __builtin_bit_cast(bfrag, BH1);                           \
    bl[0] = __builtin_bit_cast(bfrag, BL0);                           \
    bl[1] = __builtin_bit_cast(bfrag, BL1);                           \
    _Pragma("unroll")                                                 \
    for (int mi = 0; mi < 2; ++mi)                                    \
    _Pragma("unroll")                                                 \
    for (int ni = 0; ni < 2; ++ni) {                                  \
        acc[mi][ni] = __builtin_amdgcn_mfma_f32_16x16x32_bf16(        \
            ah[mi], bh[ni], acc[mi][ni], 0, 0, 0);                    \
        acc[mi][ni] = __builtin_amdgcn_mfma_f32_16x16x32_bf16(        \
            ah[mi], bl[ni], acc[mi][ni], 0, 0, 0);                    \
        acc[mi][ni] = __builtin_amdgcn_mfma_f32_16x16x32_bf16(        \
            al[mi], bh[ni], acc[mi][ni], 0, 0, 0);                    \
    } } while (0)

    // ---- prologue: chunk0 -> buf0; prefetch chunk1 (A reg, B reg)
    float4 xa0 = *(const float4*)(Xp);
    uint4 bh00, bh01, bl00, bl01;
    LDB(bh00, bh01, bl00, bl01, 0);
    float4 xa1 = *(const float4*)(Xp + 32);
    uint4 bh10, bh11, bl10, bl11;
    LDB(bh10, bh11, bl10, bl11, 1);
    WRA(0, xa0);
    __syncthreads();

    for (int c2 = 0; c2 < 8; ++c2) {
        // ---- even chunk 2*c2 (buf0, B regs set 0)
        WRA(1, xa1);                                   // stage odd chunk 2*c2+1
        if (c2 < 7) xa0 = *(const float4*)(Xp + (2 * c2 + 2) * 32);
        COMP(0, bh00, bh01, bl00, bl01);
        if (c2 < 7) LDB(bh00, bh01, bl00, bl01, 2 * c2 + 2);
        __syncthreads();                               // buf1 ready; buf0 free
        // ---- odd chunk 2*c2+1 (buf1, B regs set 1)
        if (c2 < 7) WRA(0, xa0);                       // stage even chunk 2*c2+2
        COMP(1, bh10, bh11, bl10, bl11);
        if (c2 < 7) {
            xa1 = *(const float4*)(Xp + (2 * c2 + 3) * 32);
            LDB(bh10, bh11, bl10, bl11, 2 * c2 + 3);
        }
        __syncthreads();                               // buf0 ready; buf1 free
    }
#undef WRA
#undef LDB
#undef COMP

    // ---- epilogue: bias + exp2, dword stores (lanes 0-15 contiguous cols)
    const float SC = 2.885390081777926815f;   // 2*log2(e)
    float bcol[2];
#pragma unroll
    for (int ni = 0; ni < 2; ++ni) bcol[ni] = bias[nb * 128 + w * 32 + ni * 16 + lr];

#pragma unroll
    for (int mi = 0; mi < 2; ++mi)
#pragma unroll
        for (int ni = 0; ni < 2; ++ni) {
            const int col = nb * 128 + w * 32 + ni * 16 + lr;
#pragma unroll
            for (int r = 0; r < 4; ++r) {
                const int row = row0 + mi * 16 + lk * 4 + r;
                out[(size_t)row * 256 + col] =
                    __builtin_amdgcn_exp2f(SC * (acc[mi][ni][r] + bcol[ni]));
            }
        }
}

// ---------------------------------------------------------------------------
// sr[b][q][m] = sum_h wl[h] / (Eq[b][q][h]*Ek[b][m][h] + 1)
// (tanh folded: tanh(v) = 1 - 2/(e^{2v}+1); exp precomputed -> p = fma(Ek,Eq,1))
// 4-way reciprocal grouping: sum w_i/p_i = N/(p0 p1 p2 p3) -> 1 rcp per 4 h.
// Block: 256 threads; m-tile 128 (lane m = tid&127), q-octet split in halves
// (qh = tid>>7 -> 4 q's per thread). Eq tile + wl staged ONCE in LDS;
// Ek chunked 16-h with quad-blocked layout for aligned ds_read_b128.
// Grid 1024 blocks (4/CU); b = bid&7 for XCD L2 affinity on Ek.
// ---------------------------------------------------------------------------
__global__ __launch_bounds__(256) void logits_kernel(
    const float* __restrict__ Eq, const float* __restrict__ Ek,
    const float* __restrict__ wl, float* __restrict__ sr) {
    const int bid = blockIdx.x;
    const int b  = bid & 7;
    const int r2 = bid >> 3;
    const int mt = r2 & 7;      // m tile of 128
    const int qt = r2 >> 3;     // q octet
    const int tid = threadIdx.x;
    const int m  = tid & 127;
    const int qh = tid >> 7;    // 0/1: which 4 q's

    __shared__ float eqs[2048];        // [j][h], j<8
    __shared__ float wls[256];
    __shared__ float kq[4][128][4];    // [h-quad][m][4], 16B-aligned slots

    const float* qpb = Eq + ((size_t)(b * QL_ + qt * 8)) * H_;
    const float* kpb = Ek + ((size_t)(b * ML_ + mt * 128)) * H_;

    // one-time stage: Eq tile (2048 contiguous floats) + wl (256 floats)
    *(float4*)(&eqs[tid * 4])        = *(const float4*)(qpb + tid * 4);
    *(float4*)(&eqs[1024 + tid * 4]) = *(const float4*)(qpb + 1024 + tid * 4);
    if (tid < 64) *(float4*)(&wls[tid * 4]) = *(const float4*)(wl + tid * 4);

    // Ek staging map: lane covers row srow, h-range [8*sq2, 8*sq2+8) of chunk
    const int srow = tid & 127;
    const int sq2  = tid >> 7;
    const float* kst = kpb + (size_t)srow * H_ + 8 * sq2;
    float4 a0 = *(const float4*)(kst);
    float4 a1 = *(const float4*)(kst + 4);

    float acc[4] = {0.f, 0.f, 0.f, 0.f};

    for (int c = 0; c < 16; ++c) {
        __syncthreads();
        *(float4*)(&kq[2 * sq2 + 0][srow][0]) = a0;
        *(float4*)(&kq[2 * sq2 + 1][srow][0]) = a1;
        __syncthreads();
        if (c < 15) {
            a0 = *(const float4*)(kst + (c + 1) * 16);
            a1 = *(const float4*)(kst + (c + 1) * 16 + 4);
        }
        const int h0 = c * 16;
#pragma unroll
        for (int quad = 0; quad < 4; ++quad) {
            float4 k4 = *(const float4*)(&kq[quad][m][0]);
            float4 w4 = *(const float4*)(&wls[h0 + quad * 4]);
#pragma unroll
            for (int j2 = 0; j2 < 4; ++j2) {
                float4 q4 = *(const float4*)(&eqs[(qh * 4 + j2) * 256 + h0 + quad * 4]);
                float p0 = fmaf(k4.x, q4.x, 1.0f);
                float p1 = fmaf(k4.y, q4.y, 1.0f);
                float p2 = fmaf(k4.z, q4.z, 1.0f);
                float p3 = fmaf(k4.w, q4.w, 1.0f);
                float p01 = p0 * p1, p23 = p2 * p3;
                float n01 = fmaf(w4.y, p0, w4.x * p1);
                float n23 = fmaf(w4.w, p2, w4.z * p3);
                float Nm  = fmaf(n23, p01, n01 * p23);
                float P   = p01 * p23;
                acc[j2] = fmaf(Nm, __builtin_amdgcn_rcpf(P), acc[j2]);
            }
        }
    }
#pragma unroll
    for (int j2 = 0; j2 < 4; ++j2)
        sr[((size_t)(b * QL_ + qt * 8 + qh * 4 + j2)) * ML_ + mt * 128 + m] = acc[j2];
}

// ---------------------------------------------------------------------------
// In-place masked softmax (unchanged). logits_eff = -2*sr (shift-invariant).
// ---------------------------------------------------------------------------
__global__ __launch_bounds__(256) void softmax_kernel(
    float* __restrict__ wrow_io, const unsigned char* __restrict__ mv) {
    const int row = blockIdx.x;
    const int b = row >> 7;
    const int tid = threadIdx.x;
    float* srow = wrow_io + (size_t)row * ML_;
    const unsigned char* mrow = mv + b * ML_;
    __shared__ float red[4];

    float4 s4 = *(const float4*)(srow + tid * 4);
    uchar4 m4 = *(const uchar4*)(mrow + tid * 4);
    float l[4];
    l[0] = m4.x ? -1e18f : -2.0f * s4.x;
    l[1] = m4.y ? -1e18f : -2.0f * s4.y;
    l[2] = m4.z ? -1e18f : -2.0f * s4.z;
    l[3] = m4.w ? -1e18f : -2.0f * s4.w;

    float mx = fmaxf(fmaxf(l[0], l[1]), fmaxf(l[2], l[3]));
#pragma unroll
    for (int off = 32; off >= 1; off >>= 1)
        mx = fmaxf(mx, __shfl_xor(mx, off));
    if ((tid & 63) == 0) red[tid >> 6] = mx;
    __syncthreads();
    mx = fmaxf(fmaxf(red[0], red[1]), fmaxf(red[2], red[3]));
    __syncthreads();

    const float L2E = 1.44269504088896340736f;
    float e[4], s = 0.f;
#pragma unroll
    for (int i = 0; i < 4; ++i) {
        e[i] = __builtin_amdgcn_exp2f((l[i] - mx) * L2E);
        s += e[i];
    }
#pragma unroll
    for (int off = 32; off >= 1; off >>= 1)
        s += __shfl_xor(s, off);
    if ((tid & 63) == 0) red[tid >> 6] = s;
    __syncthreads();
    s = (red[0] + red[1]) + (red[2] + red[3]);
    float inv = __builtin_amdgcn_rcpf(s);
    float4 o = make_float4(e[0] * inv, e[1] * inv, e[2] * inv, e[3] * inv);
    *(float4*)(srow + tid * 4) = o;
}

// ---------------------------------------------------------------------------
// attns[b] = W[b] (128x1024) @ M[b] (1024x512). LDS-tiled GEMM (unchanged).
// ---------------------------------------------------------------------------
__global__ __launch_bounds__(256) void attn_out_kernel(
    const float* __restrict__ wgt, const float* __restrict__ mem,
    float* __restrict__ out) {
    const int bid = blockIdx.x;
    const int b  = bid & 7;
    const int j2 = bid >> 3;
    const int mt = j2 & 3;
    const int nt = j2 >> 2;
    const int t = threadIdx.x;
    __shared__ float As[32][34];
    __shared__ float Bs[32][64];

    const int ar = t >> 3, ac = (t & 7) << 2;
    const int br = t >> 4, bc = (t & 15) << 2;
    const float* Ap = wgt + ((size_t)(b * QL_ + mt * 32 + ar)) * ML_ + ac;
    const float* Bp = mem + ((size_t)(b * ML_ + br)) * KS_ + nt * 64 + bc;

    const int tx = t & 15, ty = t >> 4;
    float acc0[4] = {0.f, 0.f, 0.f, 0.f};
    float acc1[4] = {0.f, 0.f, 0.f, 0.f};

    float4 apre = *(const float4*)(Ap);
    float4 bpre0 = *(const float4*)(Bp);
    float4 bpre1 = *(const float4*)(Bp + (size_t)16 * KS_);

    for (int k0 = 0; k0 < ML_; k0 += 32) {
        __syncthreads();
        As[ac + 0][ar] = apre.x; As[ac + 1][ar] = apre.y;
        As[ac + 2][ar] = apre.z; As[ac + 3][ar] = apre.w;
        *(float4*)(&Bs[br][bc])      = bpre0;
        *(float4*)(&Bs[br + 16][bc]) = bpre1;
        __syncthreads();
        if (k0 + 32 < ML_) {
            apre  = *(const float4*)(Ap + k0 + 32);
            bpre0 = *(const float4*)(Bp + (size_t)(k0 + 32) * KS_);
            bpre1 = *(const float4*)(Bp + (size_t)(k0 + 48) * KS_);
        }
#pragma unroll
        for (int kk = 0; kk < 32; ++kk) {
            float2 a2 = *(const float2*)(&As[kk][ty * 2]);
            float4 b4 = *(const float4*)(&Bs[kk][tx * 4]);
            acc0[0] = fmaf(a2.x, b4.x, acc0[0]);
            acc0[1] = fmaf(a2.x, b4.y, acc0[1]);
            acc0[2] = fmaf(a2.x, b4.z, acc0[2]);
            acc0[3] = fmaf(a2.x, b4.w, acc0[3]);
            acc1[0] = fmaf(a2.y, b4.x, acc1[0]);
            acc1[1] = fmaf(a2.y, b4.y, acc1[1]);
            acc1[2] = fmaf(a2.y, b4.z, acc1[2]);
            acc1[3] = fmaf(a2.y, b4.w, acc1[3]);
        }
    }
    size_t orow = ((size_t)(b * QL_ + mt * 32 + ty * 2)) * KS_ + nt * 64 + tx * 4;
    *(float4*)(out + orow)       = make_float4(acc0[0], acc0[1], acc0[2], acc0[3]);
    *(float4*)(out + orow + KS_) = make_float4(acc1[0], acc1[1], acc1[2], acc1[3]);
}

extern "C" void kernel_launch(void* const* d_in, const int* in_sizes, int n_in,
                              void* d_out, int out_size, void* d_ws, size_t ws_size,
                              hipStream_t stream) {
    const float* query  = (const float*)d_in[0];
    const float* memory = (const float*)d_in[1];
    const unsigned char* mask = (const unsigned char*)d_in[2];
    const float* Wq = (const float*)d_in[3];
    const float* bq = (const float*)d_in[4];
    const float* Wk = (const float*)d_in[5];
    const float* bk = (const float*)d_in[6];
    const float* wl = (const float*)d_in[7];
    // d_in[8] (bl) cancels under softmax shift-invariance; not read.

    float* ws = (float*)d_ws;
    float* Eq = ws + QP_OFF;
    float* Ek = ws + KP_OFF;
    unsigned char* mcan = (unsigned char*)(ws + MASK_OFF);
    unsigned short* Whi = (unsigned short*)(ws + WH_OFF);
    unsigned short* Wlo = (unsigned short*)(ws + WL_OFF);

    float* attns = (float*)d_out;                      // [B][QL][KS]
    float* wout  = (float*)d_out + B_ * QL_ * KS_;     // [B][QL][ML] (also sr scratch)

    prep_kernel<<<dim3(65),  dim3(256), 0, stream>>>(Wq, Wk, Whi, Wlo, mask, mcan);
    proj_kernel<<<dim3(576), dim3(256), 0, stream>>>(query, memory, Whi, Wlo,
                                                     bq, bk, Eq, Ek);
    logits_kernel<<<dim3(1024), dim3(256), 0, stream>>>(Eq, Ek, wl, wout);
    softmax_kernel<<<dim3(B_ * QL_), dim3(256), 0, stream>>>(wout, mcan);
    attn_out_kernel<<<dim3(256), dim3(256), 0, stream>>>(wout, memory, attns);
}